// Round 5
// baseline (386.805 us; speedup 1.0000x reference)
//
#include <hip/hip_runtime.h>
#include <math.h>

#define EC_N 64
// exp(-0.5*q) == exp2(q * -0.5*log2(e)); fold the scale into the coefficients
#define NEG_HALF_LOG2E (-0.72134752044448170368f)
#define NEG_LOG2E      (-1.44269504088896340736f)

typedef float v4f __attribute__((ext_vector_type(4)));

struct __align__(16) NerfParam {
    float c00, c11, c22, c01_2;
    float c02_2, c12_2, cx, cy;
    float cz, cc, pad0, pad1;
};

__device__ __forceinline__ float fast_exp2(float x) { return __builtin_amdgcn_exp2f(x); }
__device__ __forceinline__ float fast_rcp(float x)  { return __builtin_amdgcn_rcpf(x); }
__device__ __forceinline__ v4f nt_load(const v4f* p) { return __builtin_nontemporal_load(p); }

__global__ void init_penalty_kernel(const float* __restrict__ centers,
                                    float* __restrict__ pen_out) {
    int e = threadIdx.x;
    float p = 0.f;
    if (e < EC_N) {
        const float bmax[3] = {0.6f, 0.6f, 0.6f};
        const float bmin[3] = {-0.6f, -0.6f, -0.35f};
        #pragma unroll
        for (int k = 0; k < 3; ++k) {
            float cv = centers[e * 3 + k];
            p += fmaxf(cv - bmax[k], 0.f) + fmaxf(bmin[k] - cv, 0.f);
        }
    }
    #pragma unroll
    for (int off = 32; off > 0; off >>= 1)
        p += __shfl_down(p, off, 64);
    if (threadIdx.x == 0) *pen_out = p;   // main kernel atomicAdds on top
}

__global__ __launch_bounds__(256, 4) void rbf_main_kernel(
    const float* __restrict__ wsp,        // [N,3]
    const float* __restrict__ act,        // [EC,N,4]
    const float* __restrict__ dists,      // [N,1]
    const float* __restrict__ constants,  // [EC,1]
    const float* __restrict__ centers,    // [EC,3]
    const float* __restrict__ radii,      // [EC,3]
    const float* __restrict__ rotations,  // [EC,3]
    float* __restrict__ out,              // [N,4]
    float* __restrict__ pen,              // scalar (pre-initialized with bbox term)
    int n)
{
    __shared__ NerfParam sp[EC_N];
    __shared__ float s_pen[4];

    const int tid = threadIdx.x;

    if (tid < EC_N) {
        const int e = tid;
        float c = fabsf(constants[e]);
        float r0 = fabsf(radii[e * 3 + 0]) + 0.005f;
        float r1 = fabsf(radii[e * 3 + 1]) + 0.005f;
        float r2 = fabsf(radii[e * 3 + 2]) + 0.005f;
        float d0 = 1.f / (r0 + 1e-8f);
        float d1 = 1.f / (r1 + 1e-8f);
        float d2 = 1.f / (r2 + 1e-8f);
        float ax = rotations[e * 3 + 0];
        float ay = rotations[e * 3 + 1];
        float az = rotations[e * 3 + 2];
        float sx, cx, sy, cy, sz, cz;
        sincosf(ax, &sx, &cx);
        sincosf(ay, &sy, &cy);
        sincosf(az, &sz, &cz);
        float R00 = cz * cy;
        float R01 = cz * sy * sx - sz * cx;
        float R02 = cz * sy * cx + sz * sx;
        float R10 = sz * cy;
        float R11 = sz * sy * sx + cz * cx;
        float R12 = sz * sy * cx - cz * sx;
        float R20 = -sy;
        float R21 = cy * sx;
        float R22 = cy * cx;
        const float k = NEG_HALF_LOG2E;
        float c00 = (R00 * R00 * d0 + R01 * R01 * d1 + R02 * R02 * d2) * k;
        float c11 = (R10 * R10 * d0 + R11 * R11 * d1 + R12 * R12 * d2) * k;
        float c22 = (R20 * R20 * d0 + R21 * R21 * d1 + R22 * R22 * d2) * k;
        float c01 = (R00 * R10 * d0 + R01 * R11 * d1 + R02 * R12 * d2) * k;
        float c02 = (R00 * R20 * d0 + R01 * R21 * d1 + R02 * R22 * d2) * k;
        float c12 = (R10 * R20 * d0 + R11 * R21 * d1 + R12 * R22 * d2) * k;
        NerfParam p;
        p.c00 = c00; p.c11 = c11; p.c22 = c22;
        p.c01_2 = 2.f * c01; p.c02_2 = 2.f * c02; p.c12_2 = 2.f * c12;
        p.cx = centers[e * 3 + 0];
        p.cy = centers[e * 3 + 1];
        p.cz = centers[e * 3 + 2];
        p.cc = c;
        p.pad0 = 0.f; p.pad1 = 0.f;
        sp[e] = p;
    }
    __syncthreads();

    const int i = blockIdx.x * 256 + tid;   // one point per thread
    const bool ok = i < n;
    const int j = ok ? i : 0;
    const int half = n >> 1;
    const int j2 = (j < half) ? (j + half) : (j - half);   // disjoint half: L2-miss guaranteed

    const float px = wsp[j * 3 + 0];
    const float py = wsp[j * 3 + 1];
    const float pz = wsp[j * 3 + 2];
    const float dl = dists[j] * NEG_LOG2E;  // <= 0 always at runtime
    const float rz = fmaxf(dl, 0.f);        // runtime zero the compiler can't prove

    // two real e-streams (e in [0,32) and [32,64)), prefetch distance 2 each
    const v4f* plo = (const v4f*)act + j;
    const v4f* phi = (const v4f*)act + ((size_t)32 * n + j);
    // two mirrored DIAGNOSTIC streams at j2 (same rows, other half of i)
    const v4f* qlo = (const v4f*)act + j2;
    const v4f* qhi = (const v4f*)act + ((size_t)32 * n + j2);

    v4f A0 = nt_load(plo); plo += n;
    v4f B0 = nt_load(phi); phi += n;
    v4f D0 = nt_load(qlo); qlo += n;
    v4f E0 = nt_load(qhi); qhi += n;
    v4f A1 = nt_load(plo); plo += n;
    v4f B1 = nt_load(phi); phi += n;
    v4f D1 = nt_load(qlo); qlo += n;
    v4f E1 = nt_load(qhi); qhi += n;

    float S = 0.f, v0 = 0.f, v1 = 0.f, v2 = 0.f, v3 = 0.f, penL = 0.f;

    #pragma unroll 2
    for (int e = 0; e < 32; ++e) {
        const v4f aLo = A0; A0 = A1;
        const v4f aHi = B0; B0 = B1;
        const v4f dLo = D0; D0 = D1;
        const v4f dHi = E0; E0 = E1;
        if (e < 30) {                       // uniform branch: prefetch e+2 / e+34
            A1 = nt_load(plo); plo += n;
            B1 = nt_load(phi); phi += n;
            D1 = nt_load(qlo); qlo += n;
            E1 = nt_load(qhi); qhi += n;
        }

        // fold diagnostic loads with runtime-zero weight (no numerical effect)
        penL = fmaf(dLo.x + dLo.y + dLo.z + dLo.w
                  + dHi.x + dHi.y + dHi.z + dHi.w, rz, penL);

        // ---- stream lo: nerflet e ----
        {
            const NerfParam p = sp[e];
            const float x = px - p.cx, y = py - p.cy, z = pz - p.cz;
            float q = x * x * p.c00;
            q = fmaf(y * y, p.c11, q);
            q = fmaf(z * z, p.c22, q);
            q = fmaf(x * y, p.c01_2, q);
            q = fmaf(x * z, p.c02_2, q);
            q = fmaf(y * z, p.c12_2, q);
            const float rbf = fast_exp2(q) * p.cc;
            S += rbf;
            penL += fmaxf(rbf - 0.01f, 0.f);
            const float s0 = fast_rcp(1.f + fast_exp2(aLo.x * NEG_LOG2E));
            const float s1 = fast_rcp(1.f + fast_exp2(aLo.y * NEG_LOG2E));
            const float s2 = fast_rcp(1.f + fast_exp2(aLo.z * NEG_LOG2E));
            const float al = 1.f - fast_exp2(fmaxf(aLo.w, 0.f) * dl);
            v0 = fmaf(rbf, s0, v0);
            v1 = fmaf(rbf, s1, v1);
            v2 = fmaf(rbf, s2, v2);
            v3 = fmaf(rbf, al, v3);
        }
        // ---- stream hi: nerflet e+32 ----
        {
            const NerfParam p = sp[e + 32];
            const float x = px - p.cx, y = py - p.cy, z = pz - p.cz;
            float q = x * x * p.c00;
            q = fmaf(y * y, p.c11, q);
            q = fmaf(z * z, p.c22, q);
            q = fmaf(x * y, p.c01_2, q);
            q = fmaf(x * z, p.c02_2, q);
            q = fmaf(y * z, p.c12_2, q);
            const float rbf = fast_exp2(q) * p.cc;
            S += rbf;
            penL += fmaxf(rbf - 0.01f, 0.f);
            const float s0 = fast_rcp(1.f + fast_exp2(aHi.x * NEG_LOG2E));
            const float s1 = fast_rcp(1.f + fast_exp2(aHi.y * NEG_LOG2E));
            const float s2 = fast_rcp(1.f + fast_exp2(aHi.z * NEG_LOG2E));
            const float al = 1.f - fast_exp2(fmaxf(aHi.w, 0.f) * dl);
            v0 = fmaf(rbf, s0, v0);
            v1 = fmaf(rbf, s1, v1);
            v2 = fmaf(rbf, s2, v2);
            v3 = fmaf(rbf, al, v3);
        }
    }

    if (ok) {
        const float inv = fast_rcp(S + 1e-6f);
        v4f o; o.x = v0 * inv; o.y = v1 * inv; o.z = v2 * inv; o.w = v3 * inv;
        __builtin_nontemporal_store(o, (v4f*)out + i);
    }

    float penLocal = ok ? penL : 0.f;
    #pragma unroll
    for (int off = 32; off > 0; off >>= 1)
        penLocal += __shfl_down(penLocal, off, 64);
    const int wave = tid >> 6;
    const int lane = tid & 63;
    if (lane == 0) s_pen[wave] = penLocal;
    __syncthreads();
    if (tid == 0) {
        const float t = s_pen[0] + s_pen[1] + s_pen[2] + s_pen[3];
        atomicAdd(pen, t * (0.001f / (float)n));
    }
}

extern "C" void kernel_launch(void* const* d_in, const int* in_sizes, int n_in,
                              void* d_out, int out_size, void* d_ws, size_t ws_size,
                              hipStream_t stream) {
    const float* wsp       = (const float*)d_in[0];
    const float* act       = (const float*)d_in[1];
    const float* dists     = (const float*)d_in[2];
    const float* constants = (const float*)d_in[3];
    const float* centers   = (const float*)d_in[4];
    const float* radii     = (const float*)d_in[5];
    const float* rotations = (const float*)d_in[6];

    const int n = in_sizes[0] / 3;           // world_space_points is [N,3]
    float* out = (float*)d_out;              // [N,4] flat
    float* pen = out + (size_t)n * 4;        // scalar penalty at the end

    init_penalty_kernel<<<1, 64, 0, stream>>>(centers, pen);

    const int blocks = (n + 255) / 256;      // 1 point per thread, 1024 blocks
    rbf_main_kernel<<<blocks, 256, 0, stream>>>(
        wsp, act, dists, constants, centers, radii, rotations, out, pen, n);
}